// Round 8
// baseline (15906.657 us; speedup 1.0000x reference)
//
#include <hip/hip_runtime.h>

#define NCONE 8
#define NDIM 24          // NC*3
#define PGD_ITERS 100
#define BATCH 65536
#define BLOCKT 256       // 1 elem/thread; 1024 waves = 1 wave/SIMD chip-wide
#define POW_ITERS 80
#define NPK 150          // 300 upper-triangle entries of symmetric P, fp16 pairs

typedef _Float16 half2v __attribute__((ext_vector_type(2)));

__device__ __forceinline__ float fast_rsq(float x) { return __builtin_amdgcn_rsqf(x); }

// ---- band-major enumeration of the upper triangle -------------------------
// d = j-i ascending; within a band, i ascending. Consecutive entries hit
// distinct accumulator targets (no RMW stalls in the FMA stream).
constexpr int b2i(int u) {
    int d = 0;
    while (u >= NDIM - d) { u -= NDIM - d; ++d; }
    return u;
}
constexpr int b2j(int u) {
    int d = 0;
    while (u >= NDIM - d) { u -= NDIM - d; ++d; }
    return u + d;
}

// SOC projection, rsqrt-only form (validated R7: absmax 0.031).
__device__ __forceinline__ void soc_proj(float& t, float& x0, float& x1) {
    float n2  = fmaf(x0, x0, x1 * x1);
    float n2s = fmaxf(n2, 1e-30f);
    float rsq = fast_rsq(n2s);
    float n   = n2s * rsq;
    float coef = 0.5f * (t + n);
    float sc   = coef * rsq;
    bool inside = (n <= t);
    bool below  = (n <= -t);
    float tn = inside ? t    : (below ? 0.0f : coef);
    float s  = inside ? 1.0f : (below ? 0.0f : sc);
    t = tn; x0 *= s; x1 *= s;
}

// g(f32) += li(f32) * f16-half of pk — one full-rate VALU op (validated R6/R7).
#define FMA_MIX_LO(g_, li_, pk_)                                               \
    asm("v_fma_mix_f32 %0, %1, %2, %0 op_sel:[0,0,0] op_sel_hi:[0,1,0]"        \
        : "+v"(g_) : "v"(li_), "v"(pk_))
#define FMA_MIX_HI(g_, li_, pk_)                                               \
    asm("v_fma_mix_f32 %0, %1, %2, %0 op_sel:[0,1,0] op_sel_hi:[0,1,0]"        \
        : "+v"(g_) : "v"(li_), "v"(pk_))

// ---------------------------------------------------------------------------
// Fused kernel, v8.
//
// R1: LICM hoist of LDS-P -> scratch spill, 836 us.
// R2: LDS broadcast @1 wave/SIMD: latency exposed, 349 us.
// R3: 2 elem/thread -> half the SIMDs idle, 396 us.
// R4: SMEM-streamed P: s_load stalls, 878 us.
// R5: f16 P "in regs": allocator chose AGPRs + cvt path, 338 us.
// R6: inline v_fma_mix: still AGPR-parked, one shuttle copy PER USE, 304 us.
// R7: band-major + 2nd accumulator: allocator spilled P to SCRATCH, 14 ms.
// Lesson: with 150 long-lived values the RA must be DICTATED to, not hinted.
//
// v8: P is pinned in AGPRs explicitly ("a"-constrained v_accvgpr_write at
// pack time). Per iteration, exactly 150 volatile v_accvgpr_read shuttles
// (one per packed reg, NOT one per use), each feeding 2-4 v_fma_mix ops.
// Volatile reads cannot be hoisted/CSE'd across iterations (closes R1).
// Arch-VGPR pressure ~120 -> no spill possible. ~920 VALU insts/iter
// ~= 1850 cyc -> ~77 us loop @ 1 wave/SIMD.
// ---------------------------------------------------------------------------
__global__ __launch_bounds__(BLOCKT, 1) void pgd_fused(const float* __restrict__ P,
                                                       const float* __restrict__ q,
                                                       float* __restrict__ out) {
    __shared__ __align__(16) float sP[NDIM * NDIM];   // staging: pow-iter + pack
    __shared__ float sQ[BLOCKT * (NDIM + 1)];         // coalescing buffer, stride 25

    const int tid  = threadIdx.x;
    const int base = blockIdx.x * (BLOCKT * NDIM);

    for (int i = tid; i < NDIM * NDIM; i += BLOCKT)
        sP[i] = P[i];
    for (int idx = tid; idx < BLOCKT * NDIM; idx += BLOCKT) {
        int r = idx / NDIM;
        int c = idx - r * NDIM;
        sQ[r * (NDIM + 1) + c] = q[base + idx];
    }
    __syncthreads();

    // --- step = 1/lambda_max(P): per-wave power iteration + Rayleigh ---
    // (zero inter-block state — R2's graph-replay divergence lesson)
    const int lane = tid & 63;
    float step;
    {
        float p[NDIM];
#pragma unroll
        for (int j = 0; j < NDIM; ++j)
            p[j] = (lane < NDIM) ? sP[lane * NDIM + j] : 0.0f;
        float v = (lane < NDIM) ? (1.0f + 0.01f * (float)lane) : 0.0f;

        for (int it = 0; it < POW_ITERS; ++it) {
            float w = 0.0f;
#pragma unroll
            for (int j = 0; j < NDIM; ++j)
                w = fmaf(p[j], __shfl(v, j, 64), w);
            float n2 = w * w;
#pragma unroll
            for (int off = 32; off >= 1; off >>= 1)
                n2 += __shfl_xor(n2, off, 64);
            v = w * rsqrtf(n2);
        }
        float w = 0.0f;
#pragma unroll
        for (int j = 0; j < NDIM; ++j)
            w = fmaf(p[j], __shfl(v, j, 64), w);
        float num = v * w;
        float den = v * v;
#pragma unroll
        for (int off = 32; off >= 1; off >>= 1) {
            num += __shfl_xor(num, off, 64);
            den += __shfl_xor(den, off, 64);
        }
        step = den / num;   // identical on every lane/wave/block
    }

    // --- pack upper triangle (band-major, fp16 pairs) and PIN in AGPRs ---
    unsigned pa[NPK];   // each element def'd by "=a" asm -> AGPR class
#pragma unroll
    for (int k = 0; k < NPK; ++k) {
        float a = sP[b2i(2 * k)     * NDIM + b2j(2 * k)];
        float b = sP[b2i(2 * k + 1) * NDIM + b2j(2 * k + 1)];
        half2v hv;
        hv[0] = (_Float16)a;
        hv[1] = (_Float16)b;
        unsigned val = __builtin_bit_cast(unsigned, hv);
        asm volatile("v_accvgpr_write_b32 %0, %1" : "=a"(pa[k]) : "v"(val));
    }

    // --- per-thread state (arch VGPRs, ~120 total live) ---
    float lq[NDIM], l[NDIM];
#pragma unroll
    for (int j = 0; j < NDIM; ++j) {
        lq[j] = sQ[tid * (NDIM + 1) + j];
        l[j]  = 0.0f;
    }

#pragma clang loop unroll(disable)
    for (int it = 0; it < PGD_ITERS; ++it) {
        float g[NDIM];
#pragma unroll
        for (int j = 0; j < NDIM; ++j)
            g[j] = lq[j];

        // g += P l — per packed reg: ONE volatile AGPR->VGPR shuttle, then
        // 2-4 v_fma_mix uses. 150 reads + 600 FMAs per iteration.
#pragma unroll
        for (int k = 0; k < NPK; ++k) {
            unsigned pk;
            asm volatile("v_accvgpr_read_b32 %0, %1" : "=v"(pk) : "a"(pa[k]));
#pragma unroll
            for (int hf = 0; hf < 2; ++hf) {
                const int u = 2 * k + hf;    // compile-time under full unroll
                const int i = b2i(u);
                const int j = b2j(u);
                if (i == j) {
                    if (hf == 0) { FMA_MIX_LO(g[i], l[i], pk); }
                    else         { FMA_MIX_HI(g[i], l[i], pk); }
                } else {
                    if (hf == 0) { FMA_MIX_LO(g[j], l[i], pk);
                                   FMA_MIX_LO(g[i], l[j], pk); }
                    else         { FMA_MIX_HI(g[j], l[i], pk);
                                   FMA_MIX_HI(g[i], l[j], pk); }
                }
            }
        }

        // y = l - step*g
#pragma unroll
        for (int j = 0; j < NDIM; ++j)
            g[j] = fmaf(-step, g[j], l[j]);

        // project onto product of 8 SOCs
#pragma unroll
        for (int c = 0; c < NCONE; ++c)
            soc_proj(g[c], g[NCONE + 2 * c], g[NCONE + 2 * c + 1]);

#pragma unroll
        for (int j = 0; j < NDIM; ++j)
            l[j] = g[j];
    }

    // --- coalesced store through padded LDS ---
    __syncthreads();
#pragma unroll
    for (int j = 0; j < NDIM; ++j)
        sQ[tid * (NDIM + 1) + j] = l[j];
    __syncthreads();
    for (int idx = tid; idx < BLOCKT * NDIM; idx += BLOCKT) {
        int r = idx / NDIM;
        int c = idx - r * NDIM;
        out[base + idx] = sQ[r * (NDIM + 1) + c];
    }
}

extern "C" void kernel_launch(void* const* d_in, const int* in_sizes, int n_in,
                              void* d_out, int out_size, void* d_ws, size_t ws_size,
                              hipStream_t stream) {
    const float* P = (const float*)d_in[0];   // (1, 24, 24) fp32
    const float* q = (const float*)d_in[1];   // (65536, 24, 1) fp32
    float* out     = (float*)d_out;           // (65536, 24) fp32
    (void)d_ws; (void)ws_size;

    pgd_fused<<<BATCH / BLOCKT, BLOCKT, 0, stream>>>(P, q, out);
}

// Round 9
// 13696.413 us; speedup vs baseline: 1.1614x; 1.1614x over previous
//
#include <hip/hip_runtime.h>

#define NCONE 8
#define NDIM 24          // NC*3
#define PGD_ITERS 100
#define BATCH 65536
#define BLOCKT 256       // 1 elem/thread; 1024 waves = 1 wave/SIMD chip-wide
#define POW_ITERS 48
#define NPAIR 150        // 300 upper-triangle entries, fp16-packed 2/word
#define NW4 38           // ceil(152/4) uint4 words (2 zero-pad words)

typedef _Float16 half2v __attribute__((ext_vector_type(2)));

__device__ __forceinline__ float fast_rsq(float x) { return __builtin_amdgcn_rsqf(x); }

// ---- band-major enumeration of the upper triangle -------------------------
// d = j-i ascending; within a band, i ascending. Consecutive FMA targets are
// distinct (g walks ascending; mirrors go to h) -> no RMW dependency chains.
constexpr int b2i(int u) {
    int d = 0;
    while (u >= NDIM - d) { u -= NDIM - d; ++d; }
    return u;
}
constexpr int b2j(int u) {
    int d = 0;
    while (u >= NDIM - d) { u -= NDIM - d; ++d; }
    return u + d;
}

// SOC projection, rsqrt-only form (validated R7/R8: absmax 0.031).
__device__ __forceinline__ void soc_proj(float& t, float& x0, float& x1) {
    float n2  = fmaf(x0, x0, x1 * x1);
    float n2s = fmaxf(n2, 1e-30f);
    float rsq = fast_rsq(n2s);
    float n   = n2s * rsq;
    float coef = 0.5f * (t + n);
    float sc   = coef * rsq;
    bool inside = (n <= t);
    bool below  = (n <= -t);
    float tn = inside ? t    : (below ? 0.0f : coef);
    float s  = inside ? 1.0f : (below ? 0.0f : sc);
    t = tn; x0 *= s; x1 *= s;
}

// g(f32) += li(f32) * f16-half of pk — one full-rate VALU op (validated R6+).
#define FMA_MIX_LO(g_, li_, pk_)                                               \
    asm("v_fma_mix_f32 %0, %1, %2, %0 op_sel:[0,0,0] op_sel_hi:[0,1,0]"        \
        : "+v"(g_) : "v"(li_), "v"(pk_))
#define FMA_MIX_HI(g_, li_, pk_)                                               \
    asm("v_fma_mix_f32 %0, %1, %2, %0 op_sel:[0,1,0] op_sel_hi:[0,1,0]"        \
        : "+v"(g_) : "v"(li_), "v"(pk_))

// ---------------------------------------------------------------------------
// Fused kernel, v9.
//
// History: R1 LICM spill 836us | R2 LDS fp32 broadcast 349us (WORKS, LDS-
// issue-bound: 144 b128/wave-iter) | R3 fewer waves 396us | R4 SMEM 878us |
// R5-R8 register-resident P: RA parks in AGPR w/ per-use shuttle (304us) or
// spills to scratch (14-16ms). Lesson: never hand the RA 150 long-lived
// values; never put P anywhere but LDS.
//
// v9 = R2's proven structure with 3.8x fewer LDS ops: symmetric triangle
// (576->300 values) x fp16 packing (2/word) = 38 uint4 broadcast reads per
// wave-iter (vs 144). Mirrored accumulation into h[] (band-major -> no RMW
// chains), v_fma_mix consumes packed halves directly. Per-iter memory
// clobber keeps reads in-loop (R2-proven, no spill: only ~16 P words live).
// LDS/CU-iter 1824 cyc ~ VALU/SIMD-iter 1600 cyc -> balanced, ~85-115us.
// ---------------------------------------------------------------------------
__global__ __launch_bounds__(BLOCKT, 1) void pgd_fused(const float* __restrict__ P,
                                                       const float* __restrict__ q,
                                                       float* __restrict__ out) {
    __shared__ __align__(16) float sP[NDIM * NDIM];     // fp32 staging (pow-iter)
    __shared__ __align__(16) unsigned sTri[4 * NW4];    // fp16-pair triangle, band-major
    __shared__ float sQ[BLOCKT * (NDIM + 1)];           // coalescing buffer, stride 25

    const int tid  = threadIdx.x;
    const int base = blockIdx.x * (BLOCKT * NDIM);

    for (int i = tid; i < NDIM * NDIM; i += BLOCKT)
        sP[i] = P[i];
    for (int idx = tid; idx < BLOCKT * NDIM; idx += BLOCKT) {
        int r = idx / NDIM;
        int c = idx - r * NDIM;
        sQ[r * (NDIM + 1) + c] = q[base + idx];
    }
    __syncthreads();

    // --- pack triangle into LDS (runs once; b2i/b2j fine at runtime) ---
    if (tid < 4 * NW4) {
        unsigned val = 0;
        if (tid < NPAIR) {
            float a = sP[b2i(2 * tid)     * NDIM + b2j(2 * tid)];
            float b = sP[b2i(2 * tid + 1) * NDIM + b2j(2 * tid + 1)];
            half2v hv;
            hv[0] = (_Float16)a;
            hv[1] = (_Float16)b;
            val = __builtin_bit_cast(unsigned, hv);
        }
        sTri[tid] = val;
    }

    // --- step = 1/lambda_max(P): per-wave power iteration + Rayleigh ---
    // (zero inter-block state — R2's graph-replay divergence lesson)
    const int lane = tid & 63;
    float step;
    {
        float p[NDIM];
#pragma unroll
        for (int j = 0; j < NDIM; ++j)
            p[j] = (lane < NDIM) ? sP[lane * NDIM + j] : 0.0f;
        float v = (lane < NDIM) ? (1.0f + 0.01f * (float)lane) : 0.0f;

        for (int it = 0; it < POW_ITERS; ++it) {
            float w = 0.0f;
#pragma unroll
            for (int j = 0; j < NDIM; ++j)
                w = fmaf(p[j], __shfl(v, j, 64), w);
            float n2 = w * w;
#pragma unroll
            for (int off = 32; off >= 1; off >>= 1)
                n2 += __shfl_xor(n2, off, 64);
            v = w * rsqrtf(n2);
        }
        float w = 0.0f;
#pragma unroll
        for (int j = 0; j < NDIM; ++j)
            w = fmaf(p[j], __shfl(v, j, 64), w);
        float num = v * w;
        float den = v * v;
#pragma unroll
        for (int off = 32; off >= 1; off >>= 1) {
            num += __shfl_xor(num, off, 64);
            den += __shfl_xor(den, off, 64);
        }
        step = den / num;   // identical on every lane/wave/block
    }
    __syncthreads();        // sTri visible to all waves

    // --- per-thread state (~140 VGPRs live, far from the cliff) ---
    float lq[NDIM], l[NDIM];
#pragma unroll
    for (int j = 0; j < NDIM; ++j) {
        lq[j] = sQ[tid * (NDIM + 1) + j];
        l[j]  = 0.0f;
    }

    const uint4* sT4 = (const uint4*)sTri;

#pragma clang loop unroll(disable)
    for (int it = 0; it < PGD_ITERS; ++it) {
        // Keep the (loop-invariant) triangle reads inside this iteration —
        // defeats LICM register blowup (R1/R2-proven).
        asm volatile("" ::: "memory");

        float g[NDIM], h[NDIM];
#pragma unroll
        for (int j = 0; j < NDIM; ++j) {
            g[j] = lq[j];
            h[j] = 0.0f;
        }

        // g/h += P l — 38 broadcast uint4 LDS reads, 576 v_fma_mix.
#pragma unroll
        for (int w = 0; w < NW4; ++w) {
            uint4 t4 = sT4[w];
#pragma unroll
            for (int c = 0; c < 4; ++c) {
                const int k = 4 * w + c;          // pair index, compile-time
                if (k >= NPAIR) continue;
                unsigned pk = (c == 0) ? t4.x : (c == 1) ? t4.y
                            : (c == 2) ? t4.z : t4.w;
#pragma unroll
                for (int hf = 0; hf < 2; ++hf) {
                    const int u = 2 * k + hf;
                    const int i = b2i(u);
                    const int j = b2j(u);
                    if (i == j) {
                        if (hf == 0) { FMA_MIX_LO(g[i], l[i], pk); }
                        else         { FMA_MIX_HI(g[i], l[i], pk); }
                    } else {
                        if (hf == 0) { FMA_MIX_LO(g[j], l[i], pk);
                                       FMA_MIX_LO(h[i], l[j], pk); }
                        else         { FMA_MIX_HI(g[j], l[i], pk);
                                       FMA_MIX_HI(h[i], l[j], pk); }
                    }
                }
            }
        }

        // y = l - step*(g + h)   (g already contains lq)
#pragma unroll
        for (int j = 0; j < NDIM; ++j)
            g[j] = fmaf(-step, g[j] + h[j], l[j]);

        // project onto product of 8 SOCs
#pragma unroll
        for (int c = 0; c < NCONE; ++c)
            soc_proj(g[c], g[NCONE + 2 * c], g[NCONE + 2 * c + 1]);

#pragma unroll
        for (int j = 0; j < NDIM; ++j)
            l[j] = g[j];
    }

    // --- coalesced store through padded LDS ---
    __syncthreads();
#pragma unroll
    for (int j = 0; j < NDIM; ++j)
        sQ[tid * (NDIM + 1) + j] = l[j];
    __syncthreads();
    for (int idx = tid; idx < BLOCKT * NDIM; idx += BLOCKT) {
        int r = idx / NDIM;
        int c = idx - r * NDIM;
        out[base + idx] = sQ[r * (NDIM + 1) + c];
    }
}

extern "C" void kernel_launch(void* const* d_in, const int* in_sizes, int n_in,
                              void* d_out, int out_size, void* d_ws, size_t ws_size,
                              hipStream_t stream) {
    const float* P = (const float*)d_in[0];   // (1, 24, 24) fp32
    const float* q = (const float*)d_in[1];   // (65536, 24, 1) fp32
    float* out     = (float*)d_out;           // (65536, 24) fp32
    (void)d_ws; (void)ws_size;

    pgd_fused<<<BATCH / BLOCKT, BLOCKT, 0, stream>>>(P, q, out);
}

// Round 11
// 261.873 us; speedup vs baseline: 60.7418x; 52.3016x over previous
//
#include <hip/hip_runtime.h>

#define NCONE 8
#define NDIM 24          // NC*3
#define PGD_ITERS 100
#define BATCH 65536
#define BLOCKT 256       // 1 elem/thread; 1024 waves = 1 wave/SIMD chip-wide
#define POW_ITERS 48
#define NWORD 288        // 24x24 fp16 values, 2 per 32-bit word

typedef _Float16 half2v __attribute__((ext_vector_type(2)));

__device__ __forceinline__ float fast_rsq(float x) { return __builtin_amdgcn_rsqf(x); }

// SOC projection, rsqrt-only form (validated R7-R9: absmax 0.031).
__device__ __forceinline__ void soc_proj(float& t, float& x0, float& x1) {
    float n2  = fmaf(x0, x0, x1 * x1);
    float n2s = fmaxf(n2, 1e-30f);
    float rsq = fast_rsq(n2s);
    float n   = n2s * rsq;
    float coef = 0.5f * (t + n);
    float sc   = coef * rsq;
    bool inside = (n <= t);
    bool below  = (n <= -t);
    float tn = inside ? t    : (below ? 0.0f : coef);
    float s  = inside ? 1.0f : (below ? 0.0f : sc);
    t = tn; x0 *= s; x1 *= s;
}

// g(f32) += li(f32) * f16-half of pk — one full-rate VALU op (validated R6+).
#define FMA_MIX_LO(g_, li_, pk_)                                               \
    asm("v_fma_mix_f32 %0, %1, %2, %0 op_sel:[0,0,0] op_sel_hi:[0,1,0]"        \
        : "+v"(g_) : "v"(li_), "v"(pk_))
#define FMA_MIX_HI(g_, li_, pk_)                                               \
    asm("v_fma_mix_f32 %0, %1, %2, %0 op_sel:[0,1,0] op_sel_hi:[0,1,0]"        \
        : "+v"(g_) : "v"(li_), "v"(pk_))

// ---------------------------------------------------------------------------
// Fused kernel, v11 (= v10 + pack-bounds fix).
//
// History: R1 LICM spill 836us | R2 LDS fp32 broadcast 349us (PROVEN SHAPE)
// | R3 396us | R4 SMEM 878us | R5-R8 register-resident P: AGPR shuttle
// (304us) or scratch (14-16ms) | R9 fp16 triangle + 2nd accumulator:
// SROA collapse -> scratch, 13.7ms | R10 NaN: pack step wrote only
// tid<256 of 288 words (BLOCKT=256!) — uninitialized LDS, structure untested.
//
// v11 = R2's exact loop shape with fp16-packed FULL P (row-major, affine
// indexing, single g accumulator): 72 ds_read_b128/wave-iter (2x fewer than
// R2), v_fma_mix consumes packed halves with compile-time op_sel. No
// symmetry trick (needs the 2nd accumulator that spilled R7/R9).
// LDS/CU-iter = 4x72x12 = 3456 cyc -> ~144us wall; VALU ~1550 cyc/SIMD-iter
// overlapped under it. Predict 160-220us stable.
// ---------------------------------------------------------------------------
__global__ __launch_bounds__(BLOCKT, 1) void pgd_fused(const float* __restrict__ P,
                                                       const float* __restrict__ q,
                                                       float* __restrict__ out) {
    __shared__ __align__(16) float sP[NDIM * NDIM];   // fp32 staging (pow-iter)
    __shared__ __align__(16) unsigned sPh[NWORD];     // fp16-pair P, row-major
    __shared__ float sQ[BLOCKT * (NDIM + 1)];         // coalescing buffer, stride 25

    const int tid  = threadIdx.x;
    const int base = blockIdx.x * (BLOCKT * NDIM);

    for (int i = tid; i < NDIM * NDIM; i += BLOCKT)
        sP[i] = P[i];
    for (int idx = tid; idx < BLOCKT * NDIM; idx += BLOCKT) {
        int r = idx / NDIM;
        int c = idx - r * NDIM;
        sQ[r * (NDIM + 1) + c] = q[base + idx];
    }
    __syncthreads();

    // --- pack P as fp16 pairs, row-major (STRIDED: NWORD=288 > BLOCKT=256,
    // the R10 bug — a plain `if (tid < NWORD)` left words 256..287 garbage)
    for (int w = tid; w < NWORD; w += BLOCKT) {
        half2v hv;
        hv[0] = (_Float16)sP[2 * w];
        hv[1] = (_Float16)sP[2 * w + 1];
        sPh[w] = __builtin_bit_cast(unsigned, hv);
    }

    // --- step = 1/lambda_max(P): per-wave power iteration + Rayleigh ---
    // (zero inter-block state — R2's graph-replay divergence lesson)
    const int lane = tid & 63;
    float step;
    {
        float p[NDIM];
#pragma unroll
        for (int j = 0; j < NDIM; ++j)
            p[j] = (lane < NDIM) ? sP[lane * NDIM + j] : 0.0f;
        float v = (lane < NDIM) ? (1.0f + 0.01f * (float)lane) : 0.0f;

        for (int it = 0; it < POW_ITERS; ++it) {
            float w = 0.0f;
#pragma unroll
            for (int j = 0; j < NDIM; ++j)
                w = fmaf(p[j], __shfl(v, j, 64), w);
            float n2 = w * w;
#pragma unroll
            for (int off = 32; off >= 1; off >>= 1)
                n2 += __shfl_xor(n2, off, 64);
            v = w * rsqrtf(n2);
        }
        float w = 0.0f;
#pragma unroll
        for (int j = 0; j < NDIM; ++j)
            w = fmaf(p[j], __shfl(v, j, 64), w);
        float num = v * w;
        float den = v * v;
#pragma unroll
        for (int off = 32; off >= 1; off >>= 1) {
            num += __shfl_xor(num, off, 64);
            den += __shfl_xor(den, off, 64);
        }
        step = den / num;   // identical on every lane/wave/block
    }
    __syncthreads();        // sPh visible to all waves

    // --- per-thread state (R2-proven pressure: ~100 VGPRs) ---
    float lq[NDIM], l[NDIM];
#pragma unroll
    for (int j = 0; j < NDIM; ++j) {
        lq[j] = sQ[tid * (NDIM + 1) + j];
        l[j]  = 0.0f;
    }

    const uint4* sPh4 = (const uint4*)sPh;

#pragma clang loop unroll(disable)
    for (int it = 0; it < PGD_ITERS; ++it) {
        // Keep the (loop-invariant) P reads inside this iteration —
        // defeats LICM register blowup (R1/R2-proven).
        asm volatile("" ::: "memory");

        float g[NDIM];
#pragma unroll
        for (int j = 0; j < NDIM; ++j)
            g[j] = lq[j];

        // g += P^T l (P symmetric): row i scaled by l[i]. 3 uint4 reads and
        // 24 v_fma_mix per row; all indices affine — nothing to choke on.
#pragma unroll
        for (int i = 0; i < NDIM; ++i) {
            float li = l[i];
            uint4 w0 = sPh4[3 * i + 0];
            uint4 w1 = sPh4[3 * i + 1];
            uint4 w2 = sPh4[3 * i + 2];
            FMA_MIX_LO(g[0],  li, w0.x); FMA_MIX_HI(g[1],  li, w0.x);
            FMA_MIX_LO(g[2],  li, w0.y); FMA_MIX_HI(g[3],  li, w0.y);
            FMA_MIX_LO(g[4],  li, w0.z); FMA_MIX_HI(g[5],  li, w0.z);
            FMA_MIX_LO(g[6],  li, w0.w); FMA_MIX_HI(g[7],  li, w0.w);
            FMA_MIX_LO(g[8],  li, w1.x); FMA_MIX_HI(g[9],  li, w1.x);
            FMA_MIX_LO(g[10], li, w1.y); FMA_MIX_HI(g[11], li, w1.y);
            FMA_MIX_LO(g[12], li, w1.z); FMA_MIX_HI(g[13], li, w1.z);
            FMA_MIX_LO(g[14], li, w1.w); FMA_MIX_HI(g[15], li, w1.w);
            FMA_MIX_LO(g[16], li, w2.x); FMA_MIX_HI(g[17], li, w2.x);
            FMA_MIX_LO(g[18], li, w2.y); FMA_MIX_HI(g[19], li, w2.y);
            FMA_MIX_LO(g[20], li, w2.z); FMA_MIX_HI(g[21], li, w2.z);
            FMA_MIX_LO(g[22], li, w2.w); FMA_MIX_HI(g[23], li, w2.w);
        }

        // y = l - step*g
#pragma unroll
        for (int j = 0; j < NDIM; ++j)
            g[j] = fmaf(-step, g[j], l[j]);

        // project onto product of 8 SOCs
#pragma unroll
        for (int c = 0; c < NCONE; ++c)
            soc_proj(g[c], g[NCONE + 2 * c], g[NCONE + 2 * c + 1]);

#pragma unroll
        for (int j = 0; j < NDIM; ++j)
            l[j] = g[j];
    }

    // --- coalesced store through padded LDS ---
    __syncthreads();
#pragma unroll
    for (int j = 0; j < NDIM; ++j)
        sQ[tid * (NDIM + 1) + j] = l[j];
    __syncthreads();
    for (int idx = tid; idx < BLOCKT * NDIM; idx += BLOCKT) {
        int r = idx / NDIM;
        int c = idx - r * NDIM;
        out[base + idx] = sQ[r * (NDIM + 1) + c];
    }
}

extern "C" void kernel_launch(void* const* d_in, const int* in_sizes, int n_in,
                              void* d_out, int out_size, void* d_ws, size_t ws_size,
                              hipStream_t stream) {
    const float* P = (const float*)d_in[0];   // (1, 24, 24) fp32
    const float* q = (const float*)d_in[1];   // (65536, 24, 1) fp32
    float* out     = (float*)d_out;           // (65536, 24) fp32
    (void)d_ws; (void)ws_size;

    pgd_fused<<<BATCH / BLOCKT, BLOCKT, 0, stream>>>(P, q, out);
}